// Round 15
// baseline (43.797 us; speedup 1.0000x reference)
//
#include <hip/hip_runtime.h>
#include <hip/hip_bf16.h>

#define NB 2
#define C_IN 64
#define N_SP 32768
#define NHEADS 4
#define DH 32
#define HID 128
#define QK_SCALE 0.17677669529663687f  // 32^-0.5
#define GN_EPS_C 1e-5f
#define NGN 2097152.0f                  // 64*32768

using bf16x8 = __attribute__((ext_vector_type(8))) short;
using f32x4  = __attribute__((ext_vector_type(4))) float;
using u16x4  = __attribute__((ext_vector_type(4))) unsigned short;
using u16x8  = __attribute__((ext_vector_type(8))) unsigned short;

__device__ __forceinline__ unsigned short f2bf(float f) {
    union { float f; unsigned u; } c{f};
    unsigned r = c.u + 0x7FFFu + ((c.u >> 16) & 1u);   // RNE
    return (unsigned short)(r >> 16);
}
__device__ __forceinline__ float bf2f(unsigned short u) {
    union { unsigned u; float f; } c{ (unsigned)u << 16 };
    return c.f;
}

// wave's x fragments: lane holds x[kk*32+lg*8+j][n0+s*16+lc]  (32 positions)
__device__ __forceinline__ void load_xf(const float* __restrict__ xb, int n0,
        int lg, int lc, bf16x8 xf[2][2]) {
#pragma unroll
    for (int s = 0; s < 2; ++s) {
        int n = n0 + s * 16 + lc;
#pragma unroll
        for (int kk = 0; kk < 2; ++kk) {
            bf16x8 v;
#pragma unroll
            for (int j = 0; j < 8; ++j)
                v[j] = (short)f2bf(xb[(size_t)(kk * 32 + lg * 8 + j) * N_SP + n]);
            xf[s][kk] = v;
        }
    }
}

// ==== kA: qkv per 256-pos block; q̂ -> global frag blobs; k/v -> ctx ========
__global__ __launch_bounds__(512) void kA(const float* __restrict__ x,
        const float* __restrict__ wqkv, unsigned short* __restrict__ qs_frag,
        float* __restrict__ ctx_part, float* __restrict__ ksum_part) {
    __shared__ unsigned short wl[3072 * 8];      // all w frags (q,k,v), 48 KB
    __shared__ unsigned short kt[2][8192];       // [ch 32][pos 256] swizzled, dbuf
    __shared__ unsigned short vt[2][8192];
    const int t = threadIdx.x, wv = t >> 6, l = t & 63, lg = l >> 4, lc = l & 15;
    const int blk = blockIdx.x;
    const int b = blk >> 7, nblk = blk & 127;
    const int n0 = nblk * 256 + wv * 32;

    // x loads FIRST: longest-latency (HBM) loads issue before the L2 w-stage
    bf16x8 xf[2][2];
    load_xf(x + (size_t)b * C_IN * N_SP, n0, lg, lc, xf);

    // stage ALL w rows 0..383 into bf16 MFMA A-frag layout (frag f = mt*2+kk)
#pragma unroll
    for (int i = 0; i < 6; ++i) {
        int idx = t + i * 512;          // 0..3071 = (frag, lane)
        int f = idx >> 6, lane = idx & 63;
        int row = (f >> 1) * 16 + (lane & 15);
        int c0 = (f & 1) * 32 + (lane >> 4) * 8;
        const float* wp = wqkv + row * 64 + c0;
        u16x8 pk;
#pragma unroll
        for (int j = 0; j < 8; ++j) pk[j] = f2bf(wp[j]);
        *(u16x8*)(wl + (size_t)idx * 8) = pk;
    }
    __syncthreads();

    // ---- q phase: softmax (no max-sub; |q|<~10 so exp is safe) ----
#pragma unroll
    for (int h = 0; h < NHEADS; ++h) {
        f32x4 qa[2][2] = {};   // [mi][s]
#pragma unroll
        for (int mi = 0; mi < 2; ++mi)
#pragma unroll
            for (int kk = 0; kk < 2; ++kk) {
                bf16x8 aq = *(const bf16x8*)(wl + ((size_t)((h * 2 + mi) * 2 + kk) * 64 + l) * 8);
#pragma unroll
                for (int s = 0; s < 2; ++s)
                    qa[mi][s] = __builtin_amdgcn_mfma_f32_16x16x32_bf16(aq, xf[s][kk], qa[mi][s], 0, 0, 0);
            }
#pragma unroll
        for (int s = 0; s < 2; ++s) {
            float sum = 0.f;
#pragma unroll
            for (int mi = 0; mi < 2; ++mi)
#pragma unroll
                for (int r = 0; r < 4; ++r) {
                    float e = __expf(qa[mi][s][r]);
                    qa[mi][s][r] = e; sum += e;
                }
            sum += __shfl_xor(sum, 16);
            sum += __shfl_xor(sum, 32);
            float inv = QK_SCALE / sum;
            int pos16 = nblk * 16 + wv * 2 + s;
            unsigned short* blob = qs_frag + ((size_t)(b * 2048 + pos16) * 4 + h) * 512;
#pragma unroll
            for (int mi = 0; mi < 2; ++mi) {
                u16x4 pk;
#pragma unroll
                for (int r = 0; r < 4; ++r) pk[r] = f2bf(qa[mi][s][r] * inv);
                int lanep = (mi * 2 + (lg >> 1)) * 16 + lc;
                *(u16x4*)(blob + (size_t)lanep * 8 + (lg & 1) * 4) = pk;
            }
        }
    }

    // ---- k/v + ctx phase ----
    const int di = (wv >> 1) & 1, ei = wv & 1;   // ctx quadrant (waves 0..3)
#pragma unroll
    for (int h = 0; h < NHEADS; ++h) {
        const int bs = h & 1;
        f32x4 ka[2][2] = {}, va[2][2] = {};   // [s][e]
#pragma unroll
        for (int e = 0; e < 2; ++e)
#pragma unroll
            for (int kk = 0; kk < 2; ++kk) {
                bf16x8 wk = *(const bf16x8*)(wl + ((size_t)((8 + 2 * h + e) * 2 + kk) * 64 + l) * 8);
                bf16x8 wf = *(const bf16x8*)(wl + ((size_t)((16 + 2 * h + e) * 2 + kk) * 64 + l) * 8);
#pragma unroll
                for (int s = 0; s < 2; ++s) {
                    ka[s][e] = __builtin_amdgcn_mfma_f32_16x16x32_bf16(xf[s][kk], wk, ka[s][e], 0, 0, 0);
                    va[s][e] = __builtin_amdgcn_mfma_f32_16x16x32_bf16(xf[s][kk], wf, va[s][e], 0, 0, 0);
                }
            }
#pragma unroll
        for (int s = 0; s < 2; ++s)
#pragma unroll
            for (int e = 0; e < 2; ++e) {
                u16x4 pk, pv;
#pragma unroll
                for (int r = 0; r < 4; ++r) {
                    pk[r] = f2bf(__expf(ka[s][e][r]));
                    pv[r] = f2bf(va[s][e][r]);
                }
                int ch = e * 16 + lc;
                int pos = wv * 32 + s * 16 + lg * 4;
                int ba = (ch * 512 + pos * 2) ^ ((ch & 7) << 4);
                *(u16x4*)((char*)kt[bs] + ba) = pk;
                *(u16x4*)((char*)vt[bs] + ba) = pv;
            }
        __syncthreads();
        if (wv < 4) {
            f32x4 ca = {};
            float ks = 0.f;
#pragma unroll
            for (int k0 = 0; k0 < 256; k0 += 32) {
                int ar = di * 16 + lc, br = ei * 16 + lc;
                bf16x8 af = *(const bf16x8*)((const char*)kt[bs] + ((ar * 512 + (k0 + lg * 8) * 2) ^ ((ar & 7) << 4)));
                bf16x8 bf = *(const bf16x8*)((const char*)vt[bs] + ((br * 512 + (k0 + lg * 8) * 2) ^ ((br & 7) << 4)));
                if (ei == 0) {
#pragma unroll
                    for (int j = 0; j < 8; ++j) ks += bf2f((unsigned short)af[j]);
                }
                ca = __builtin_amdgcn_mfma_f32_16x16x32_bf16(af, bf, ca, 0, 0, 0);
            }
            float* cp = ctx_part + ((size_t)(b * 4 + h) * 128 + nblk) * 1024;
#pragma unroll
            for (int r = 0; r < 4; ++r)
                cp[(di * 16 + lg * 4 + r) * 32 + ei * 16 + lc] = ca[r];
            if (ei == 0) {
                ks += __shfl_xor(ks, 16);
                ks += __shfl_xor(ks, 32);
                if (lg == 0)
                    ksum_part[((size_t)(b * 4 + h) * 128 + nblk) * 32 + di * 16 + lc] = ks;
            }
        }
    }
}

// ==== kB: reduce ctx/ksum, Weff = wout·(ctx/ksum)  (256 blocks, 1 d each) ===
__global__ __launch_bounds__(256) void kB(const float* __restrict__ ctx_part,
        const float* __restrict__ ksum_part, const float* __restrict__ wout,
        unsigned short* __restrict__ weff) {
    __shared__ float c8[8][32];
    __shared__ float cred[32];
    __shared__ float ksr[2];
    __shared__ float ksv;
    const int blk = blockIdx.x;
    const int g = blk >> 5, ds = blk & 31;    // g = b*4+h; ds = d-channel
    const int bb = g >> 2, h = g & 3;
    const int t = threadIdx.x;
    const int e = t & 31, ii = t >> 5;        // ii 0..7
    float a = 0.f;
    const float* cp = ctx_part + (size_t)g * 128 * 1024 + ds * 32 + e;
#pragma unroll 4
    for (int i = ii * 16; i < ii * 16 + 16; ++i) a += cp[(size_t)i * 1024];
    c8[ii][e] = a;
    float ks = 0.f;
    if (t < 128) ks = ksum_part[((size_t)g * 128 + t) * 32 + ds];
#pragma unroll
    for (int off = 32; off > 0; off >>= 1) ks += __shfl_down(ks, off, 64);
    if (t < 128 && (t & 63) == 0) ksr[t >> 6] = ks;
    __syncthreads();
    if (t < 32) {
        float s = 0.f;
#pragma unroll
        for (int k = 0; k < 8; ++k) s += c8[k][t];
        cred[t] = s;
    }
    if (t == 0) ksv = ksr[0] + ksr[1];
    __syncthreads();
    if (t < 64) {
        const float* wrow = wout + t * HID + h * 32;
        float acc = 0.f;
#pragma unroll
        for (int e2 = 0; e2 < 32; ++e2) acc = fmaf(wrow[e2], cred[e2], acc);
        acc /= ksv;
        weff[((size_t)bb * 64 + t) * 128 + h * 32 + ds] = f2bf(acc);
    }
}

// ==== kC: stats-only — y = Weff·q̂ in regs, s1/s2 partials (no bulk store) ==
__global__ __launch_bounds__(256) void kC(const unsigned short* __restrict__ qs_frag,
        const unsigned short* __restrict__ weff, const float* __restrict__ bout,
        float* __restrict__ pstats) {
    __shared__ float red[8];
    const int t = threadIdx.x, wv = t >> 6, l = t & 63, lg = l >> 4, lc = l & 15;
    const int blk = blockIdx.x;
    const int b = blk >> 8, nblk = blk & 255;

    f32x4 acc[4][2] = {};   // [mt][s]
    const unsigned short* wb = weff + (size_t)b * 8192;
#pragma unroll
    for (int kk = 0; kk < 4; ++kk) {
        bf16x8 bq[2];
#pragma unroll
        for (int s = 0; s < 2; ++s) {
            int pos16 = nblk * 8 + wv * 2 + s;
            bq[s] = *(const bf16x8*)(qs_frag +
                ((size_t)(b * 2048 + pos16) * 4 + kk) * 512 + (size_t)l * 8);
        }
#pragma unroll
        for (int mt = 0; mt < 4; ++mt) {
            bf16x8 af = *(const bf16x8*)(wb + (size_t)(mt * 16 + lc) * 128 + kk * 32 + lg * 8);
#pragma unroll
            for (int s = 0; s < 2; ++s)
                acc[mt][s] = __builtin_amdgcn_mfma_f32_16x16x32_bf16(af, bq[s], acc[mt][s], 0, 0, 0);
        }
    }
    float s1 = 0.f, s2 = 0.f;
#pragma unroll
    for (int mt = 0; mt < 4; ++mt) {
        float bo[4];
#pragma unroll
        for (int r = 0; r < 4; ++r) bo[r] = bout[mt * 16 + lg * 4 + r];
#pragma unroll
        for (int s = 0; s < 2; ++s)
#pragma unroll
            for (int r = 0; r < 4; ++r) {
                float val = acc[mt][s][r] + bo[r];
                s1 += val;
                s2 = fmaf(val, val, s2);
            }
    }
#pragma unroll
    for (int off = 32; off > 0; off >>= 1) {
        s1 += __shfl_down(s1, off, 64);
        s2 += __shfl_down(s2, off, 64);
    }
    if (l == 0) { red[wv * 2] = s1; red[wv * 2 + 1] = s2; }
    __syncthreads();
    if (t == 0) {
        float S1 = red[0] + red[2] + red[4] + red[6];
        float S2 = red[1] + red[3] + red[5] + red[7];
        pstats[(b * 256 + nblk) * 2]     = S1;
        pstats[(b * 256 + nblk) * 2 + 1] = S2;
    }
}

// ==== kE: recompute y via MFMA, fused bias+GN, LDS transpose, write out =====
__global__ __launch_bounds__(256) void kE(const unsigned short* __restrict__ qs_frag,
        const unsigned short* __restrict__ weff, const float* __restrict__ bout,
        const float* __restrict__ pstats, const float* __restrict__ gnw,
        const float* __restrict__ gnb, float* __restrict__ out) {
    __shared__ float red[8];
    __shared__ float ms[2];
    __shared__ float w2s[64], b2s[64];
    __shared__ float yl[128 * 65];       // padded: conflict-free transpose
    const int t = threadIdx.x, wv = t >> 6, l = t & 63, lg = l >> 4, lc = l & 15;
    const int blk = blockIdx.x;
    const int b = blk >> 8, nblk = blk & 255;

    // stats reduce (256 pairs, redundant per block, L2-hot)
    float s1 = pstats[(b * 256 + t) * 2];
    float s2 = pstats[(b * 256 + t) * 2 + 1];
#pragma unroll
    for (int off = 32; off > 0; off >>= 1) {
        s1 += __shfl_down(s1, off, 64);
        s2 += __shfl_down(s2, off, 64);
    }
    if (l == 0) { red[wv * 2] = s1; red[wv * 2 + 1] = s2; }
    __syncthreads();
    if (t == 0) {
        float S1 = red[0] + red[2] + red[4] + red[6];
        float S2 = red[1] + red[3] + red[5] + red[7];
        float mean = S1 / NGN;
        float var = S2 / NGN - mean * mean;
        ms[0] = mean; ms[1] = rsqrtf(var + GN_EPS_C);
    }
    __syncthreads();
    if (t < 64) {
        float w2 = gnw[t] * ms[1];
        w2s[t] = w2;
        b2s[t] = (bout[t] - ms[0]) * w2 + gnb[t];   // bias folded into GN
    }

    // y = Weff·q̂ (same MFMA as kC)
    f32x4 acc[4][2] = {};   // [mt][s]
    const unsigned short* wb = weff + (size_t)b * 8192;
#pragma unroll
    for (int kk = 0; kk < 4; ++kk) {
        bf16x8 bq[2];
#pragma unroll
        for (int s = 0; s < 2; ++s) {
            int pos16 = nblk * 8 + wv * 2 + s;
            bq[s] = *(const bf16x8*)(qs_frag +
                ((size_t)(b * 2048 + pos16) * 4 + kk) * 512 + (size_t)l * 8);
        }
#pragma unroll
        for (int mt = 0; mt < 4; ++mt) {
            bf16x8 af = *(const bf16x8*)(wb + (size_t)(mt * 16 + lc) * 128 + kk * 32 + lg * 8);
#pragma unroll
            for (int s = 0; s < 2; ++s)
                acc[mt][s] = __builtin_amdgcn_mfma_f32_16x16x32_bf16(af, bq[s], acc[mt][s], 0, 0, 0);
        }
    }
    __syncthreads();    // w2s/b2s ready; yl free
    // GN-applied values into LDS [pos][o] (pad 65)
#pragma unroll
    for (int mt = 0; mt < 4; ++mt)
#pragma unroll
        for (int s = 0; s < 2; ++s)
#pragma unroll
            for (int r = 0; r < 4; ++r) {
                int o = mt * 16 + lg * 4 + r;
                int pos = wv * 32 + s * 16 + lc;
                yl[pos * 65 + o] = fmaf(acc[mt][s][r], w2s[o], b2s[o]);
            }
    __syncthreads();
    // transpose write: lanes cover consecutive n -> 256 B segments per o-row
    const int p = t & 127, oh = (t >> 7) * 32;
    const int n = nblk * 128 + p;
    float* ob = out + (size_t)b * C_IN * N_SP + n;
    const float* yr = yl + p * 65 + oh;
#pragma unroll
    for (int j = 0; j < 32; ++j)
        ob[(size_t)(oh + j) * N_SP] = yr[j];
}

extern "C" void kernel_launch(void* const* d_in, const int* in_sizes, int n_in,
                              void* d_out, int out_size, void* d_ws, size_t ws_size,
                              hipStream_t stream) {
    const float* x    = (const float*)d_in[0];
    const float* wqkv = (const float*)d_in[1];
    const float* wout = (const float*)d_in[2];
    const float* bout = (const float*)d_in[3];
    const float* gnw  = (const float*)d_in[4];
    const float* gnb  = (const float*)d_in[5];
    float* out = (float*)d_out;

    char* ws = (char*)d_ws;
    size_t off = 0;
    unsigned short* qs_frag = (unsigned short*)(ws + off); off += (size_t)NB * 2048 * 4 * 512 * 2;  // 16.8 MB
    float* ctx_part  = (float*)(ws + off); off += (size_t)8 * 128 * 1024 * 4;   // 4 MB
    float* ksum_part = (float*)(ws + off); off += (size_t)8 * 128 * 32 * 4;     // 128 KB
    unsigned short* weff = (unsigned short*)(ws + off); off += 2 * 8192 * 2;    // 32 KB
    float* pstats = (float*)(ws + off); off += NB * 256 * 2 * 4;

    kA<<<dim3(256), dim3(512), 0, stream>>>(x, wqkv, qs_frag, ctx_part, ksum_part);
    kB<<<dim3(256), dim3(256), 0, stream>>>(ctx_part, ksum_part, wout, weff);
    kC<<<dim3(512), dim3(256), 0, stream>>>(qs_frag, weff, bout, pstats);
    kE<<<dim3(512), dim3(256), 0, stream>>>(qs_frag, weff, bout, pstats, gnw, gnb, out);
}

// Round 16
// 42.384 us; speedup vs baseline: 1.0334x; 1.0334x over previous
//
#include <hip/hip_runtime.h>
#include <hip/hip_bf16.h>

#define NB 2
#define C_IN 64
#define N_SP 32768
#define NHEADS 4
#define DH 32
#define HID 128
#define QK_SCALE 0.17677669529663687f  // 32^-0.5
#define GN_EPS_C 1e-5f
#define NGN 2097152.0f                  // 64*32768

using bf16x8 = __attribute__((ext_vector_type(8))) short;
using f32x4  = __attribute__((ext_vector_type(4))) float;
using u16x4  = __attribute__((ext_vector_type(4))) unsigned short;
using u16x8  = __attribute__((ext_vector_type(8))) unsigned short;

__device__ __forceinline__ unsigned short f2bf(float f) {
    union { float f; unsigned u; } c{f};
    unsigned r = c.u + 0x7FFFu + ((c.u >> 16) & 1u);   // RNE
    return (unsigned short)(r >> 16);
}
__device__ __forceinline__ float bf2f(unsigned short u) {
    union { unsigned u; float f; } c{ (unsigned)u << 16 };
    return c.f;
}

// wave's x fragments: lane holds x[kk*32+lg*8+j][n0+s*16+lc]  (32 positions)
__device__ __forceinline__ void load_xf(const float* __restrict__ xb, int n0,
        int lg, int lc, bf16x8 xf[2][2]) {
#pragma unroll
    for (int s = 0; s < 2; ++s) {
        int n = n0 + s * 16 + lc;
#pragma unroll
        for (int kk = 0; kk < 2; ++kk) {
            bf16x8 v;
#pragma unroll
            for (int j = 0; j < 8; ++j)
                v[j] = (short)f2bf(xb[(size_t)(kk * 32 + lg * 8 + j) * N_SP + n]);
            xf[s][kk] = v;
        }
    }
}

// ==== kA: qkv per 256-pos block; 64 KB LDS -> 2 blocks/CU (16 waves) ========
__global__ __launch_bounds__(512, 4) void kA(const float* __restrict__ x,
        const float* __restrict__ wqkv, unsigned short* __restrict__ qs_frag,
        float* __restrict__ ctx_part, float* __restrict__ ksum_part) {
    __shared__ unsigned short wl[2048 * 8];   // 32 KB: q frags, then k/v frags
    __shared__ unsigned short kt[8192];       // 16 KB [ch 32][pos 256] swizzled
    __shared__ unsigned short vt[8192];
    const int t = threadIdx.x, wv = t >> 6, l = t & 63, lg = l >> 4, lc = l & 15;
    const int blk = blockIdx.x;
    const int b = blk >> 7, nblk = blk & 127;
    const int n0 = nblk * 256 + wv * 32;

    // x loads FIRST: longest-latency (HBM) loads issue before the L2 w-stage
    bf16x8 xf[2][2];
    load_xf(x + (size_t)b * C_IN * N_SP, n0, lg, lc, xf);

    // stage q w-rows 0..127 (16 frags, 16 KB)
#pragma unroll
    for (int i = 0; i < 2; ++i) {
        int idx = t + i * 512;          // 0..1023 = (frag 0..15, lane)
        int f = idx >> 6, lane = idx & 63;
        int row = (f >> 1) * 16 + (lane & 15);
        int c0 = (f & 1) * 32 + (lane >> 4) * 8;
        const float* wp = wqkv + row * 64 + c0;
        u16x8 pk;
#pragma unroll
        for (int j = 0; j < 8; ++j) pk[j] = f2bf(wp[j]);
        *(u16x8*)(wl + (size_t)idx * 8) = pk;
    }
    __syncthreads();

    // ---- q phase: softmax (no max-sub; |q|<~10 so exp is safe) ----
#pragma unroll
    for (int h = 0; h < NHEADS; ++h) {
        f32x4 qa[2][2] = {};   // [mi][s]
#pragma unroll
        for (int mi = 0; mi < 2; ++mi)
#pragma unroll
            for (int kk = 0; kk < 2; ++kk) {
                bf16x8 aq = *(const bf16x8*)(wl + ((size_t)((h * 2 + mi) * 2 + kk) * 64 + l) * 8);
#pragma unroll
                for (int s = 0; s < 2; ++s)
                    qa[mi][s] = __builtin_amdgcn_mfma_f32_16x16x32_bf16(aq, xf[s][kk], qa[mi][s], 0, 0, 0);
            }
#pragma unroll
        for (int s = 0; s < 2; ++s) {
            float sum = 0.f;
#pragma unroll
            for (int mi = 0; mi < 2; ++mi)
#pragma unroll
                for (int r = 0; r < 4; ++r) {
                    float e = __expf(qa[mi][s][r]);
                    qa[mi][s][r] = e; sum += e;
                }
            sum += __shfl_xor(sum, 16);
            sum += __shfl_xor(sum, 32);
            float inv = QK_SCALE / sum;
            int pos16 = nblk * 16 + wv * 2 + s;
            unsigned short* blob = qs_frag + ((size_t)(b * 2048 + pos16) * 4 + h) * 512;
#pragma unroll
            for (int mi = 0; mi < 2; ++mi) {
                u16x4 pk;
#pragma unroll
                for (int r = 0; r < 4; ++r) pk[r] = f2bf(qa[mi][s][r] * inv);
                int lanep = (mi * 2 + (lg >> 1)) * 16 + lc;
                *(u16x4*)(blob + (size_t)lanep * 8 + (lg & 1) * 4) = pk;
            }
        }
    }
    __syncthreads();   // q-frag reads complete; wl free

    // stage k/v w-rows 128..383 (32 frags, 32 KB) over the q frags
#pragma unroll
    for (int i = 0; i < 4; ++i) {
        int idx = t + i * 512;          // 0..2047 = (frag 0..31, lane)
        int f = idx >> 6, lane = idx & 63;
        int row = (8 + (f >> 1)) * 16 + (lane & 15);
        int c0 = (f & 1) * 32 + (lane >> 4) * 8;
        const float* wp = wqkv + row * 64 + c0;
        u16x8 pk;
#pragma unroll
        for (int j = 0; j < 8; ++j) pk[j] = f2bf(wp[j]);
        *(u16x8*)(wl + (size_t)idx * 8) = pk;
    }
    __syncthreads();

    // ---- k/v + ctx phase (single-buffered kt/vt; 2 barriers/head) ----
    const int di = (wv >> 1) & 1, ei = wv & 1;   // ctx quadrant (waves 0..3)
#pragma unroll
    for (int h = 0; h < NHEADS; ++h) {
        f32x4 ka[2][2] = {}, va[2][2] = {};   // [s][e]
#pragma unroll
        for (int e = 0; e < 2; ++e)
#pragma unroll
            for (int kk = 0; kk < 2; ++kk) {
                bf16x8 wk = *(const bf16x8*)(wl + ((size_t)((2 * h + e) * 2 + kk) * 64 + l) * 8);
                bf16x8 wf = *(const bf16x8*)(wl + ((size_t)(16 + (2 * h + e) * 2 + kk) * 64 + l) * 8);
#pragma unroll
                for (int s = 0; s < 2; ++s) {
                    ka[s][e] = __builtin_amdgcn_mfma_f32_16x16x32_bf16(xf[s][kk], wk, ka[s][e], 0, 0, 0);
                    va[s][e] = __builtin_amdgcn_mfma_f32_16x16x32_bf16(xf[s][kk], wf, va[s][e], 0, 0, 0);
                }
            }
        __syncthreads();   // WAR: previous head's ctx reads complete
#pragma unroll
        for (int s = 0; s < 2; ++s)
#pragma unroll
            for (int e = 0; e < 2; ++e) {
                u16x4 pk, pv;
#pragma unroll
                for (int r = 0; r < 4; ++r) {
                    pk[r] = f2bf(__expf(ka[s][e][r]));
                    pv[r] = f2bf(va[s][e][r]);
                }
                int ch = e * 16 + lc;
                int pos = wv * 32 + s * 16 + lg * 4;
                int ba = (ch * 512 + pos * 2) ^ ((ch & 7) << 4);
                *(u16x4*)((char*)kt + ba) = pk;
                *(u16x4*)((char*)vt + ba) = pv;
            }
        __syncthreads();   // stores visible
        if (wv < 4) {
            f32x4 ca = {};
            float ks = 0.f;
#pragma unroll
            for (int k0 = 0; k0 < 256; k0 += 32) {
                int ar = di * 16 + lc, br = ei * 16 + lc;
                bf16x8 af = *(const bf16x8*)((const char*)kt + ((ar * 512 + (k0 + lg * 8) * 2) ^ ((ar & 7) << 4)));
                bf16x8 bf = *(const bf16x8*)((const char*)vt + ((br * 512 + (k0 + lg * 8) * 2) ^ ((br & 7) << 4)));
                if (ei == 0) {
#pragma unroll
                    for (int j = 0; j < 8; ++j) ks += bf2f((unsigned short)af[j]);
                }
                ca = __builtin_amdgcn_mfma_f32_16x16x32_bf16(af, bf, ca, 0, 0, 0);
            }
            float* cp = ctx_part + ((size_t)(b * 4 + h) * 128 + nblk) * 1024;
#pragma unroll
            for (int r = 0; r < 4; ++r)
                cp[(di * 16 + lg * 4 + r) * 32 + ei * 16 + lc] = ca[r];
            if (ei == 0) {
                ks += __shfl_xor(ks, 16);
                ks += __shfl_xor(ks, 32);
                if (lg == 0)
                    ksum_part[((size_t)(b * 4 + h) * 128 + nblk) * 32 + di * 16 + lc] = ks;
            }
        }
    }
}

// ==== kB: reduce ctx/ksum, Weff = wout·(ctx/ksum)  (256 blocks, 1 d each) ===
__global__ __launch_bounds__(256) void kB(const float* __restrict__ ctx_part,
        const float* __restrict__ ksum_part, const float* __restrict__ wout,
        unsigned short* __restrict__ weff) {
    __shared__ float c8[8][32];
    __shared__ float cred[32];
    __shared__ float ksr[2];
    __shared__ float ksv;
    const int blk = blockIdx.x;
    const int g = blk >> 5, ds = blk & 31;    // g = b*4+h; ds = d-channel
    const int bb = g >> 2, h = g & 3;
    const int t = threadIdx.x;
    const int e = t & 31, ii = t >> 5;        // ii 0..7
    float a = 0.f;
    const float* cp = ctx_part + (size_t)g * 128 * 1024 + ds * 32 + e;
#pragma unroll 4
    for (int i = ii * 16; i < ii * 16 + 16; ++i) a += cp[(size_t)i * 1024];
    c8[ii][e] = a;
    float ks = 0.f;
    if (t < 128) ks = ksum_part[((size_t)g * 128 + t) * 32 + ds];
#pragma unroll
    for (int off = 32; off > 0; off >>= 1) ks += __shfl_down(ks, off, 64);
    if (t < 128 && (t & 63) == 0) ksr[t >> 6] = ks;
    __syncthreads();
    if (t < 32) {
        float s = 0.f;
#pragma unroll
        for (int k = 0; k < 8; ++k) s += c8[k][t];
        cred[t] = s;
    }
    if (t == 0) ksv = ksr[0] + ksr[1];
    __syncthreads();
    if (t < 64) {
        const float* wrow = wout + t * HID + h * 32;
        float acc = 0.f;
#pragma unroll
        for (int e2 = 0; e2 < 32; ++e2) acc = fmaf(wrow[e2], cred[e2], acc);
        acc /= ksv;
        weff[((size_t)bb * 64 + t) * 128 + h * 32 + ds] = f2bf(acc);
    }
}

// ==== kC: y = Weff·q̂ from global frags; stats; y_t (pure PV, no LDS) =======
__global__ __launch_bounds__(256) void kC(const unsigned short* __restrict__ qs_frag,
        const unsigned short* __restrict__ weff, const float* __restrict__ bout,
        unsigned short* __restrict__ y_t, float* __restrict__ pstats) {
    __shared__ float red[8];
    const int t = threadIdx.x, wv = t >> 6, l = t & 63, lg = l >> 4, lc = l & 15;
    const int blk = blockIdx.x;
    const int b = blk >> 8, nblk = blk & 255;
    const int n0 = nblk * 128 + wv * 32;

    f32x4 acc[4][2] = {};   // [mt][s]
    const unsigned short* wb = weff + (size_t)b * 8192;
#pragma unroll
    for (int kk = 0; kk < 4; ++kk) {
        bf16x8 bq[2];
#pragma unroll
        for (int s = 0; s < 2; ++s) {
            int pos16 = nblk * 8 + wv * 2 + s;
            bq[s] = *(const bf16x8*)(qs_frag +
                ((size_t)(b * 2048 + pos16) * 4 + kk) * 512 + (size_t)l * 8);
        }
#pragma unroll
        for (int mt = 0; mt < 4; ++mt) {
            bf16x8 af = *(const bf16x8*)(wb + (size_t)(mt * 16 + lc) * 128 + kk * 32 + lg * 8);
#pragma unroll
            for (int s = 0; s < 2; ++s)
                acc[mt][s] = __builtin_amdgcn_mfma_f32_16x16x32_bf16(af, bq[s], acc[mt][s], 0, 0, 0);
        }
    }
    // bias + stats + y_t store ([n][o] bf16)
    float s1 = 0.f, s2 = 0.f;
#pragma unroll
    for (int mt = 0; mt < 4; ++mt) {
        float bo[4];
#pragma unroll
        for (int r = 0; r < 4; ++r) bo[r] = bout[mt * 16 + lg * 4 + r];
#pragma unroll
        for (int s = 0; s < 2; ++s) {
            u16x4 pk;
#pragma unroll
            for (int r = 0; r < 4; ++r) {
                float val = acc[mt][s][r] + bo[r];
                s1 += val;
                s2 = fmaf(val, val, s2);
                pk[r] = f2bf(val);
            }
            int n = n0 + s * 16 + lc;
            *(u16x4*)(y_t + ((size_t)b * N_SP + n) * 64 + mt * 16 + lg * 4) = pk;
        }
    }
#pragma unroll
    for (int off = 32; off > 0; off >>= 1) {
        s1 += __shfl_down(s1, off, 64);
        s2 += __shfl_down(s2, off, 64);
    }
    if (l == 0) { red[wv * 2] = s1; red[wv * 2 + 1] = s2; }
    __syncthreads();
    if (t == 0) {
        float S1 = red[0] + red[2] + red[4] + red[6];
        float S2 = red[1] + red[3] + red[5] + red[7];
        pstats[(b * 256 + nblk) * 2]     = S1;
        pstats[(b * 256 + nblk) * 2 + 1] = S2;
    }
}

// ==== kE: inline stats reduce (256 pairs), GN affine, y_t -> out ============
__global__ __launch_bounds__(256) void kE(const unsigned short* __restrict__ y_t,
        const float* __restrict__ pstats, const float* __restrict__ gnw,
        const float* __restrict__ gnb, float* __restrict__ out) {
    __shared__ float red[8];
    __shared__ float ms[2];
    __shared__ float w2s[64], b2s[64];
    const int t = threadIdx.x;
    const int blk = blockIdx.x;
    const int b = blk >> 9, nb = blk & 511;
    // reduce this batch's 256 stat pairs (redundant per block, L2-hot)
    float s1 = pstats[(b * 256 + t) * 2];
    float s2 = pstats[(b * 256 + t) * 2 + 1];
#pragma unroll
    for (int off = 32; off > 0; off >>= 1) {
        s1 += __shfl_down(s1, off, 64);
        s2 += __shfl_down(s2, off, 64);
    }
    if ((t & 63) == 0) { red[(t >> 6) * 2] = s1; red[(t >> 6) * 2 + 1] = s2; }
    __syncthreads();
    if (t == 0) {
        float S1 = red[0] + red[2] + red[4] + red[6];
        float S2 = red[1] + red[3] + red[5] + red[7];
        float mean = S1 / NGN;
        float var = S2 / NGN - mean * mean;
        ms[0] = mean; ms[1] = rsqrtf(var + GN_EPS_C);
    }
    __syncthreads();
    if (t < 64) {
        float w2 = gnw[t] * ms[1];
        w2s[t] = w2;
        b2s[t] = gnb[t] - ms[0] * w2;
    }
    __syncthreads();
    // n = nb*64 + (t&63): wave-contiguous out-writes (256 B per o-plane)
    const int n = nb * 64 + (t & 63), o0 = (t >> 6) * 16;
    const unsigned short* yp = y_t + ((size_t)b * N_SP + n) * 64 + o0;
    u16x8 v0 = *(const u16x8*)yp;
    u16x8 v1 = *(const u16x8*)(yp + 8);
    float* ob = out + (size_t)b * C_IN * N_SP + n;
#pragma unroll
    for (int j = 0; j < 8; ++j)
        ob[(size_t)(o0 + j) * N_SP] = fmaf(bf2f((unsigned short)v0[j]), w2s[o0 + j], b2s[o0 + j]);
#pragma unroll
    for (int j = 0; j < 8; ++j)
        ob[(size_t)(o0 + 8 + j) * N_SP] = fmaf(bf2f((unsigned short)v1[j]), w2s[o0 + 8 + j], b2s[o0 + 8 + j]);
}

extern "C" void kernel_launch(void* const* d_in, const int* in_sizes, int n_in,
                              void* d_out, int out_size, void* d_ws, size_t ws_size,
                              hipStream_t stream) {
    const float* x    = (const float*)d_in[0];
    const float* wqkv = (const float*)d_in[1];
    const float* wout = (const float*)d_in[2];
    const float* bout = (const float*)d_in[3];
    const float* gnw  = (const float*)d_in[4];
    const float* gnb  = (const float*)d_in[5];
    float* out = (float*)d_out;

    char* ws = (char*)d_ws;
    size_t off = 0;
    unsigned short* qs_frag = (unsigned short*)(ws + off); off += (size_t)NB * 2048 * 4 * 512 * 2;  // 16.8 MB
    float* ctx_part  = (float*)(ws + off); off += (size_t)8 * 128 * 1024 * 4;   // 4 MB
    float* ksum_part = (float*)(ws + off); off += (size_t)8 * 128 * 32 * 4;     // 128 KB
    unsigned short* weff = (unsigned short*)(ws + off); off += 2 * 8192 * 2;    // 32 KB
    unsigned short* y_t  = (unsigned short*)(ws + off); off += (size_t)NB * N_SP * 64 * 2;  // 8.4 MB
    float* pstats = (float*)(ws + off); off += NB * 256 * 2 * 4;

    kA<<<dim3(256), dim3(512), 0, stream>>>(x, wqkv, qs_frag, ctx_part, ksum_part);
    kB<<<dim3(256), dim3(256), 0, stream>>>(ctx_part, ksum_part, wout, weff);
    kC<<<dim3(512), dim3(256), 0, stream>>>(qs_frag, weff, bout, y_t, pstats);
    kE<<<dim3(1024), dim3(256), 0, stream>>>(y_t, pstats, gnw, gnb, out);
}

// Round 17
// 42.083 us; speedup vs baseline: 1.0407x; 1.0072x over previous
//
#include <hip/hip_runtime.h>
#include <hip/hip_bf16.h>

#define NB 2
#define C_IN 64
#define N_SP 32768
#define NHEADS 4
#define DH 32
#define HID 128
#define QK_SCALE 0.17677669529663687f  // 32^-0.5
#define GN_EPS_C 1e-5f
#define NGN 2097152.0f                  // 64*32768

using bf16x8 = __attribute__((ext_vector_type(8))) short;
using f32x4  = __attribute__((ext_vector_type(4))) float;
using u16x4  = __attribute__((ext_vector_type(4))) unsigned short;
using u16x8  = __attribute__((ext_vector_type(8))) unsigned short;

__device__ __forceinline__ unsigned short f2bf(float f) {
    union { float f; unsigned u; } c{f};
    unsigned r = c.u + 0x7FFFu + ((c.u >> 16) & 1u);   // RNE
    return (unsigned short)(r >> 16);
}
__device__ __forceinline__ float bf2f(unsigned short u) {
    union { unsigned u; float f; } c{ (unsigned)u << 16 };
    return c.f;
}

// ==== kA: qkv per 256-pos block; coalesced x via LDS; q̂ + ctx ==============
__global__ __launch_bounds__(512) void kA(const float* __restrict__ x,
        const float* __restrict__ wqkv, unsigned short* __restrict__ qs_frag,
        float* __restrict__ ctx_part, float* __restrict__ ksum_part) {
    __shared__ unsigned short wl[3072 * 8];      // all w frags (q,k,v), 48 KB
    __shared__ unsigned short xt[256 * 64];      // [n 256][c 64] bf16 swizzled, 32 KB
    __shared__ unsigned short kt[2][8192];       // [ch 32][pos 256] swizzled, dbuf
    __shared__ unsigned short vt[2][8192];
    const int t = threadIdx.x, wv = t >> 6, l = t & 63, lg = l >> 4, lc = l & 15;
    const int blk = blockIdx.x;
    const int b = blk >> 7, nblk = blk & 127;

    // 1) coalesced x loads FIRST (8 float4/thread covers the 64x256 fp32 tile)
    float4 xr[8];
    const float* xb = x + (size_t)b * C_IN * N_SP + nblk * 256;
#pragma unroll
    for (int i = 0; i < 8; ++i) {
        int lin = t + i * 512;              // 0..4095 float4 slots
        int row = lin >> 6, col4 = lin & 63;
        xr[i] = *(const float4*)(xb + (size_t)row * N_SP + col4 * 4);
    }

    // 2) stage ALL w rows 0..383 into bf16 MFMA A-frag layout (f = mt*2+kk)
#pragma unroll
    for (int i = 0; i < 6; ++i) {
        int idx = t + i * 512;          // 0..3071 = (frag, lane)
        int f = idx >> 6, lane = idx & 63;
        int row = (f >> 1) * 16 + (lane & 15);
        int c0 = (f & 1) * 32 + (lane >> 4) * 8;
        const float* wp = wqkv + row * 64 + c0;
        u16x8 pk;
#pragma unroll
        for (int j = 0; j < 8; ++j) pk[j] = f2bf(wp[j]);
        *(u16x8*)(wl + (size_t)idx * 8) = pk;
    }

    // 3) convert x -> bf16, store to xt [n][c] with XOR swizzle
#pragma unroll
    for (int i = 0; i < 8; ++i) {
        int lin = t + i * 512;
        int row = lin >> 6, col4 = lin & 63;
        float v[4] = { xr[i].x, xr[i].y, xr[i].z, xr[i].w };
#pragma unroll
        for (int j = 0; j < 4; ++j) {
            int n = col4 * 4 + j;
            int ba = (n * 128 + row * 2) ^ ((n & 7) << 4);
            *(unsigned short*)((char*)xt + ba) = f2bf(v[j]);
        }
    }
    __syncthreads();

    // 4) wave's x fragments from LDS (b128, <=2-way conflicts)
    bf16x8 xf[2][2];
#pragma unroll
    for (int s = 0; s < 2; ++s) {
        int n = wv * 32 + s * 16 + lc;
#pragma unroll
        for (int kk = 0; kk < 2; ++kk) {
            int ba = (n * 128 + (kk * 32 + lg * 8) * 2) ^ ((n & 7) << 4);
            xf[s][kk] = *(const bf16x8*)((const char*)xt + ba);
        }
    }

    const int n0 = nblk * 256 + wv * 32;

    // ---- q phase: softmax (no max-sub; |q|<~10 so exp is safe) ----
#pragma unroll
    for (int h = 0; h < NHEADS; ++h) {
        f32x4 qa[2][2] = {};   // [mi][s]
#pragma unroll
        for (int mi = 0; mi < 2; ++mi)
#pragma unroll
            for (int kk = 0; kk < 2; ++kk) {
                bf16x8 aq = *(const bf16x8*)(wl + ((size_t)((h * 2 + mi) * 2 + kk) * 64 + l) * 8);
#pragma unroll
                for (int s = 0; s < 2; ++s)
                    qa[mi][s] = __builtin_amdgcn_mfma_f32_16x16x32_bf16(aq, xf[s][kk], qa[mi][s], 0, 0, 0);
            }
#pragma unroll
        for (int s = 0; s < 2; ++s) {
            float sum = 0.f;
#pragma unroll
            for (int mi = 0; mi < 2; ++mi)
#pragma unroll
                for (int r = 0; r < 4; ++r) {
                    float e = __expf(qa[mi][s][r]);
                    qa[mi][s][r] = e; sum += e;
                }
            sum += __shfl_xor(sum, 16);
            sum += __shfl_xor(sum, 32);
            float inv = QK_SCALE / sum;
            int pos16 = nblk * 16 + wv * 2 + s;
            unsigned short* blob = qs_frag + ((size_t)(b * 2048 + pos16) * 4 + h) * 512;
#pragma unroll
            for (int mi = 0; mi < 2; ++mi) {
                u16x4 pk;
#pragma unroll
                for (int r = 0; r < 4; ++r) pk[r] = f2bf(qa[mi][s][r] * inv);
                int lanep = (mi * 2 + (lg >> 1)) * 16 + lc;
                *(u16x4*)(blob + (size_t)lanep * 8 + (lg & 1) * 4) = pk;
            }
        }
    }

    // ---- k/v + ctx phase (dbuf kt/vt, 1 barrier per head) ----
    const int di = (wv >> 1) & 1, ei = wv & 1;   // ctx quadrant (waves 0..3)
#pragma unroll
    for (int h = 0; h < NHEADS; ++h) {
        const int bs = h & 1;
        f32x4 ka[2][2] = {}, va[2][2] = {};   // [s][e]
#pragma unroll
        for (int e = 0; e < 2; ++e)
#pragma unroll
            for (int kk = 0; kk < 2; ++kk) {
                bf16x8 wk = *(const bf16x8*)(wl + ((size_t)((8 + 2 * h + e) * 2 + kk) * 64 + l) * 8);
                bf16x8 wf = *(const bf16x8*)(wl + ((size_t)((16 + 2 * h + e) * 2 + kk) * 64 + l) * 8);
#pragma unroll
                for (int s = 0; s < 2; ++s) {
                    ka[s][e] = __builtin_amdgcn_mfma_f32_16x16x32_bf16(xf[s][kk], wk, ka[s][e], 0, 0, 0);
                    va[s][e] = __builtin_amdgcn_mfma_f32_16x16x32_bf16(xf[s][kk], wf, va[s][e], 0, 0, 0);
                }
            }
#pragma unroll
        for (int s = 0; s < 2; ++s)
#pragma unroll
            for (int e = 0; e < 2; ++e) {
                u16x4 pk, pv;
#pragma unroll
                for (int r = 0; r < 4; ++r) {
                    pk[r] = f2bf(__expf(ka[s][e][r]));
                    pv[r] = f2bf(va[s][e][r]);
                }
                int ch = e * 16 + lc;
                int pos = wv * 32 + s * 16 + lg * 4;
                int ba = (ch * 512 + pos * 2) ^ ((ch & 7) << 4);
                *(u16x4*)((char*)kt[bs] + ba) = pk;
                *(u16x4*)((char*)vt[bs] + ba) = pv;
            }
        __syncthreads();
        if (wv < 4) {
            f32x4 ca = {};
            float ks = 0.f;
#pragma unroll
            for (int k0 = 0; k0 < 256; k0 += 32) {
                int ar = di * 16 + lc, br = ei * 16 + lc;
                bf16x8 af = *(const bf16x8*)((const char*)kt[bs] + ((ar * 512 + (k0 + lg * 8) * 2) ^ ((ar & 7) << 4)));
                bf16x8 bf = *(const bf16x8*)((const char*)vt[bs] + ((br * 512 + (k0 + lg * 8) * 2) ^ ((br & 7) << 4)));
                if (ei == 0) {
#pragma unroll
                    for (int j = 0; j < 8; ++j) ks += bf2f((unsigned short)af[j]);
                }
                ca = __builtin_amdgcn_mfma_f32_16x16x32_bf16(af, bf, ca, 0, 0, 0);
            }
            float* cp = ctx_part + ((size_t)(b * 4 + h) * 128 + nblk) * 1024;
#pragma unroll
            for (int r = 0; r < 4; ++r)
                cp[(di * 16 + lg * 4 + r) * 32 + ei * 16 + lc] = ca[r];
            if (ei == 0) {
                ks += __shfl_xor(ks, 16);
                ks += __shfl_xor(ks, 32);
                if (lg == 0)
                    ksum_part[((size_t)(b * 4 + h) * 128 + nblk) * 32 + di * 16 + lc] = ks;
            }
        }
    }
}

// ==== kB: reduce ctx/ksum, Weff = wout·(ctx/ksum)  (256 blocks, 1 d each) ===
__global__ __launch_bounds__(256) void kB(const float* __restrict__ ctx_part,
        const float* __restrict__ ksum_part, const float* __restrict__ wout,
        unsigned short* __restrict__ weff) {
    __shared__ float c8[8][32];
    __shared__ float cred[32];
    __shared__ float ksr[2];
    __shared__ float ksv;
    const int blk = blockIdx.x;
    const int g = blk >> 5, ds = blk & 31;    // g = b*4+h; ds = d-channel
    const int bb = g >> 2, h = g & 3;
    const int t = threadIdx.x;
    const int e = t & 31, ii = t >> 5;        // ii 0..7
    float a = 0.f;
    const float* cp = ctx_part + (size_t)g * 128 * 1024 + ds * 32 + e;
#pragma unroll 4
    for (int i = ii * 16; i < ii * 16 + 16; ++i) a += cp[(size_t)i * 1024];
    c8[ii][e] = a;
    float ks = 0.f;
    if (t < 128) ks = ksum_part[((size_t)g * 128 + t) * 32 + ds];
#pragma unroll
    for (int off = 32; off > 0; off >>= 1) ks += __shfl_down(ks, off, 64);
    if (t < 128 && (t & 63) == 0) ksr[t >> 6] = ks;
    __syncthreads();
    if (t < 32) {
        float s = 0.f;
#pragma unroll
        for (int k = 0; k < 8; ++k) s += c8[k][t];
        cred[t] = s;
    }
    if (t == 0) ksv = ksr[0] + ksr[1];
    __syncthreads();
    if (t < 64) {
        const float* wrow = wout + t * HID + h * 32;
        float acc = 0.f;
#pragma unroll
        for (int e2 = 0; e2 < 32; ++e2) acc = fmaf(wrow[e2], cred[e2], acc);
        acc /= ksv;
        weff[((size_t)bb * 64 + t) * 128 + h * 32 + ds] = f2bf(acc);
    }
}

// ==== kC: y = Weff·q̂ from global frags; stats; y_t (pure PV, no LDS) =======
__global__ __launch_bounds__(256) void kC(const unsigned short* __restrict__ qs_frag,
        const unsigned short* __restrict__ weff, const float* __restrict__ bout,
        unsigned short* __restrict__ y_t, float* __restrict__ pstats) {
    __shared__ float red[8];
    const int t = threadIdx.x, wv = t >> 6, l = t & 63, lg = l >> 4, lc = l & 15;
    const int blk = blockIdx.x;
    const int b = blk >> 8, nblk = blk & 255;
    const int n0 = nblk * 128 + wv * 32;

    f32x4 acc[4][2] = {};   // [mt][s]
    const unsigned short* wb = weff + (size_t)b * 8192;
#pragma unroll
    for (int kk = 0; kk < 4; ++kk) {
        bf16x8 bq[2];
#pragma unroll
        for (int s = 0; s < 2; ++s) {
            int pos16 = nblk * 8 + wv * 2 + s;
            bq[s] = *(const bf16x8*)(qs_frag +
                ((size_t)(b * 2048 + pos16) * 4 + kk) * 512 + (size_t)l * 8);
        }
#pragma unroll
        for (int mt = 0; mt < 4; ++mt) {
            bf16x8 af = *(const bf16x8*)(wb + (size_t)(mt * 16 + lc) * 128 + kk * 32 + lg * 8);
#pragma unroll
            for (int s = 0; s < 2; ++s)
                acc[mt][s] = __builtin_amdgcn_mfma_f32_16x16x32_bf16(af, bq[s], acc[mt][s], 0, 0, 0);
        }
    }
    // bias + stats + y_t store ([n][o] bf16)
    float s1 = 0.f, s2 = 0.f;
#pragma unroll
    for (int mt = 0; mt < 4; ++mt) {
        float bo[4];
#pragma unroll
        for (int r = 0; r < 4; ++r) bo[r] = bout[mt * 16 + lg * 4 + r];
#pragma unroll
        for (int s = 0; s < 2; ++s) {
            u16x4 pk;
#pragma unroll
            for (int r = 0; r < 4; ++r) {
                float val = acc[mt][s][r] + bo[r];
                s1 += val;
                s2 = fmaf(val, val, s2);
                pk[r] = f2bf(val);
            }
            int n = n0 + s * 16 + lc;
            *(u16x4*)(y_t + ((size_t)b * N_SP + n) * 64 + mt * 16 + lg * 4) = pk;
        }
    }
#pragma unroll
    for (int off = 32; off > 0; off >>= 1) {
        s1 += __shfl_down(s1, off, 64);
        s2 += __shfl_down(s2, off, 64);
    }
    if (l == 0) { red[wv * 2] = s1; red[wv * 2 + 1] = s2; }
    __syncthreads();
    if (t == 0) {
        float S1 = red[0] + red[2] + red[4] + red[6];
        float S2 = red[1] + red[3] + red[5] + red[7];
        pstats[(b * 256 + nblk) * 2]     = S1;
        pstats[(b * 256 + nblk) * 2 + 1] = S2;
    }
}

// ==== kE: inline stats reduce (256 pairs), GN affine, y_t -> out ============
__global__ __launch_bounds__(256) void kE(const unsigned short* __restrict__ y_t,
        const float* __restrict__ pstats, const float* __restrict__ gnw,
        const float* __restrict__ gnb, float* __restrict__ out) {
    __shared__ float red[8];
    __shared__ float ms[2];
    __shared__ float w2s[64], b2s[64];
    const int t = threadIdx.x;
    const int blk = blockIdx.x;
    const int b = blk >> 9, nb = blk & 511;
    // reduce this batch's 256 stat pairs (redundant per block, L2-hot)
    float s1 = pstats[(b * 256 + t) * 2];
    float s2 = pstats[(b * 256 + t) * 2 + 1];
#pragma unroll
    for (int off = 32; off > 0; off >>= 1) {
        s1 += __shfl_down(s1, off, 64);
        s2 += __shfl_down(s2, off, 64);
    }
    if ((t & 63) == 0) { red[(t >> 6) * 2] = s1; red[(t >> 6) * 2 + 1] = s2; }
    __syncthreads();
    if (t == 0) {
        float S1 = red[0] + red[2] + red[4] + red[6];
        float S2 = red[1] + red[3] + red[5] + red[7];
        float mean = S1 / NGN;
        float var = S2 / NGN - mean * mean;
        ms[0] = mean; ms[1] = rsqrtf(var + GN_EPS_C);
    }
    __syncthreads();
    if (t < 64) {
        float w2 = gnw[t] * ms[1];
        w2s[t] = w2;
        b2s[t] = gnb[t] - ms[0] * w2;
    }
    __syncthreads();
    // n = nb*64 + (t&63): wave-contiguous out-writes (256 B per o-plane)
    const int n = nb * 64 + (t & 63), o0 = (t >> 6) * 16;
    const unsigned short* yp = y_t + ((size_t)b * N_SP + n) * 64 + o0;
    u16x8 v0 = *(const u16x8*)yp;
    u16x8 v1 = *(const u16x8*)(yp + 8);
    float* ob = out + (size_t)b * C_IN * N_SP + n;
#pragma unroll
    for (int j = 0; j < 8; ++j)
        ob[(size_t)(o0 + j) * N_SP] = fmaf(bf2f((unsigned short)v0[j]), w2s[o0 + j], b2s[o0 + j]);
#pragma unroll
    for (int j = 0; j < 8; ++j)
        ob[(size_t)(o0 + 8 + j) * N_SP] = fmaf(bf2f((unsigned short)v1[j]), w2s[o0 + 8 + j], b2s[o0 + 8 + j]);
}

extern "C" void kernel_launch(void* const* d_in, const int* in_sizes, int n_in,
                              void* d_out, int out_size, void* d_ws, size_t ws_size,
                              hipStream_t stream) {
    const float* x    = (const float*)d_in[0];
    const float* wqkv = (const float*)d_in[1];
    const float* wout = (const float*)d_in[2];
    const float* bout = (const float*)d_in[3];
    const float* gnw  = (const float*)d_in[4];
    const float* gnb  = (const float*)d_in[5];
    float* out = (float*)d_out;

    char* ws = (char*)d_ws;
    size_t off = 0;
    unsigned short* qs_frag = (unsigned short*)(ws + off); off += (size_t)NB * 2048 * 4 * 512 * 2;  // 16.8 MB
    float* ctx_part  = (float*)(ws + off); off += (size_t)8 * 128 * 1024 * 4;   // 4 MB
    float* ksum_part = (float*)(ws + off); off += (size_t)8 * 128 * 32 * 4;     // 128 KB
    unsigned short* weff = (unsigned short*)(ws + off); off += 2 * 8192 * 2;    // 32 KB
    unsigned short* y_t  = (unsigned short*)(ws + off); off += (size_t)NB * N_SP * 64 * 2;  // 8.4 MB
    float* pstats = (float*)(ws + off); off += NB * 256 * 2 * 4;

    kA<<<dim3(256), dim3(512), 0, stream>>>(x, wqkv, qs_frag, ctx_part, ksum_part);
    kB<<<dim3(256), dim3(256), 0, stream>>>(ctx_part, ksum_part, wout, weff);
    kC<<<dim3(512), dim3(256), 0, stream>>>(qs_frag, weff, bout, y_t, pstats);
    kE<<<dim3(1024), dim3(256), 0, stream>>>(y_t, pstats, gnw, gnb, out);
}

// Round 18
// 41.281 us; speedup vs baseline: 1.0610x; 1.0194x over previous
//
#include <hip/hip_runtime.h>
#include <hip/hip_bf16.h>

#define NB 2
#define C_IN 64
#define N_SP 32768
#define NHEADS 4
#define DH 32
#define HID 128
#define QK_SCALE 0.17677669529663687f  // 32^-0.5
#define GN_EPS_C 1e-5f
#define NGN 2097152.0f                  // 64*32768

using bf16x8 = __attribute__((ext_vector_type(8))) short;
using f32x4  = __attribute__((ext_vector_type(4))) float;
using u16x4  = __attribute__((ext_vector_type(4))) unsigned short;
using u16x8  = __attribute__((ext_vector_type(8))) unsigned short;

__device__ __forceinline__ unsigned short f2bf(float f) {
    union { float f; unsigned u; } c{f};
    unsigned r = c.u + 0x7FFFu + ((c.u >> 16) & 1u);   // RNE
    return (unsigned short)(r >> 16);
}
__device__ __forceinline__ float bf2f(unsigned short u) {
    union { unsigned u; float f; } c{ (unsigned)u << 16 };
    return c.f;
}

// wave's x fragments: lane holds x[kk*32+lg*8+j][n0+s*16+lc]  (32 positions)
__device__ __forceinline__ void load_xf(const float* __restrict__ xb, int n0,
        int lg, int lc, bf16x8 xf[2][2]) {
#pragma unroll
    for (int s = 0; s < 2; ++s) {
        int n = n0 + s * 16 + lc;
#pragma unroll
        for (int kk = 0; kk < 2; ++kk) {
            bf16x8 v;
#pragma unroll
            for (int j = 0; j < 8; ++j)
                v[j] = (short)f2bf(xb[(size_t)(kk * 32 + lg * 8 + j) * N_SP + n]);
            xf[s][kk] = v;
        }
    }
}

// ==== kA: qkv per 256-pos block; q̂ -> global frag blobs; k/v -> ctx ========
__global__ __launch_bounds__(512) void kA(const float* __restrict__ x,
        const float* __restrict__ wqkv, unsigned short* __restrict__ qs_frag,
        float* __restrict__ ctx_part, float* __restrict__ ksum_part) {
    __shared__ unsigned short wl[3072 * 8];      // all w frags (q,k,v), 48 KB
    __shared__ unsigned short kt[2][8192];       // [ch 32][pos 256] swizzled, dbuf
    __shared__ unsigned short vt[2][8192];
    const int t = threadIdx.x, wv = t >> 6, l = t & 63, lg = l >> 4, lc = l & 15;
    const int blk = blockIdx.x;
    const int b = blk >> 7, nblk = blk & 127;
    const int n0 = nblk * 256 + wv * 32;

    // x loads FIRST: longest-latency (HBM) loads issue before the L2 w-stage
    bf16x8 xf[2][2];
    load_xf(x + (size_t)b * C_IN * N_SP, n0, lg, lc, xf);

    // stage ALL w rows 0..383 into bf16 MFMA A-frag layout (frag f = mt*2+kk)
#pragma unroll
    for (int i = 0; i < 6; ++i) {
        int idx = t + i * 512;          // 0..3071 = (frag, lane)
        int f = idx >> 6, lane = idx & 63;
        int row = (f >> 1) * 16 + (lane & 15);
        int c0 = (f & 1) * 32 + (lane >> 4) * 8;
        const float* wp = wqkv + row * 64 + c0;
        u16x8 pk;
#pragma unroll
        for (int j = 0; j < 8; ++j) pk[j] = f2bf(wp[j]);
        *(u16x8*)(wl + (size_t)idx * 8) = pk;
    }
    __syncthreads();

    // ---- q phase: softmax (no max-sub; |q|<~10 so exp is safe) ----
#pragma unroll
    for (int h = 0; h < NHEADS; ++h) {
        f32x4 qa[2][2] = {};   // [mi][s]
#pragma unroll
        for (int mi = 0; mi < 2; ++mi)
#pragma unroll
            for (int kk = 0; kk < 2; ++kk) {
                bf16x8 aq = *(const bf16x8*)(wl + ((size_t)((h * 2 + mi) * 2 + kk) * 64 + l) * 8);
#pragma unroll
                for (int s = 0; s < 2; ++s)
                    qa[mi][s] = __builtin_amdgcn_mfma_f32_16x16x32_bf16(aq, xf[s][kk], qa[mi][s], 0, 0, 0);
            }
#pragma unroll
        for (int s = 0; s < 2; ++s) {
            float sum = 0.f;
#pragma unroll
            for (int mi = 0; mi < 2; ++mi)
#pragma unroll
                for (int r = 0; r < 4; ++r) {
                    float e = __expf(qa[mi][s][r]);
                    qa[mi][s][r] = e; sum += e;
                }
            sum += __shfl_xor(sum, 16);
            sum += __shfl_xor(sum, 32);
            float inv = QK_SCALE / sum;
            int pos16 = nblk * 16 + wv * 2 + s;
            unsigned short* blob = qs_frag + ((size_t)(b * 2048 + pos16) * 4 + h) * 512;
#pragma unroll
            for (int mi = 0; mi < 2; ++mi) {
                u16x4 pk;
#pragma unroll
                for (int r = 0; r < 4; ++r) pk[r] = f2bf(qa[mi][s][r] * inv);
                int lanep = (mi * 2 + (lg >> 1)) * 16 + lc;
                *(u16x4*)(blob + (size_t)lanep * 8 + (lg & 1) * 4) = pk;
            }
        }
    }

    // ---- k/v + ctx phase ----
    const int di = (wv >> 1) & 1, ei = wv & 1;   // ctx quadrant (waves 0..3)
#pragma unroll
    for (int h = 0; h < NHEADS; ++h) {
        const int bs = h & 1;
        f32x4 ka[2][2] = {}, va[2][2] = {};   // [s][e]
#pragma unroll
        for (int e = 0; e < 2; ++e)
#pragma unroll
            for (int kk = 0; kk < 2; ++kk) {
                bf16x8 wk = *(const bf16x8*)(wl + ((size_t)((8 + 2 * h + e) * 2 + kk) * 64 + l) * 8);
                bf16x8 wf = *(const bf16x8*)(wl + ((size_t)((16 + 2 * h + e) * 2 + kk) * 64 + l) * 8);
#pragma unroll
                for (int s = 0; s < 2; ++s) {
                    ka[s][e] = __builtin_amdgcn_mfma_f32_16x16x32_bf16(xf[s][kk], wk, ka[s][e], 0, 0, 0);
                    va[s][e] = __builtin_amdgcn_mfma_f32_16x16x32_bf16(xf[s][kk], wf, va[s][e], 0, 0, 0);
                }
            }
#pragma unroll
        for (int s = 0; s < 2; ++s)
#pragma unroll
            for (int e = 0; e < 2; ++e) {
                u16x4 pk, pv;
#pragma unroll
                for (int r = 0; r < 4; ++r) {
                    pk[r] = f2bf(__expf(ka[s][e][r]));
                    pv[r] = f2bf(va[s][e][r]);
                }
                int ch = e * 16 + lc;
                int pos = wv * 32 + s * 16 + lg * 4;
                int ba = (ch * 512 + pos * 2) ^ ((ch & 7) << 4);
                *(u16x4*)((char*)kt[bs] + ba) = pk;
                *(u16x4*)((char*)vt[bs] + ba) = pv;
            }
        __syncthreads();
        if (wv < 4) {
            f32x4 ca = {};
            float ks = 0.f;
#pragma unroll
            for (int k0 = 0; k0 < 256; k0 += 32) {
                int ar = di * 16 + lc, br = ei * 16 + lc;
                bf16x8 af = *(const bf16x8*)((const char*)kt[bs] + ((ar * 512 + (k0 + lg * 8) * 2) ^ ((ar & 7) << 4)));
                bf16x8 bf = *(const bf16x8*)((const char*)vt[bs] + ((br * 512 + (k0 + lg * 8) * 2) ^ ((br & 7) << 4)));
                if (ei == 0) {
#pragma unroll
                    for (int j = 0; j < 8; ++j) ks += bf2f((unsigned short)af[j]);
                }
                ca = __builtin_amdgcn_mfma_f32_16x16x32_bf16(af, bf, ca, 0, 0, 0);
            }
            float* cp = ctx_part + ((size_t)(b * 4 + h) * 128 + nblk) * 1024;
#pragma unroll
            for (int r = 0; r < 4; ++r)
                cp[(di * 16 + lg * 4 + r) * 32 + ei * 16 + lc] = ca[r];
            if (ei == 0) {
                ks += __shfl_xor(ks, 16);
                ks += __shfl_xor(ks, 32);
                if (lg == 0)
                    ksum_part[((size_t)(b * 4 + h) * 128 + nblk) * 32 + di * 16 + lc] = ks;
            }
        }
    }
}

// ==== kB: reduce ctx/ksum, Weff = wout·(ctx/ksum)  (256 blocks, 1 d each) ===
__global__ __launch_bounds__(256) void kB(const float* __restrict__ ctx_part,
        const float* __restrict__ ksum_part, const float* __restrict__ wout,
        unsigned short* __restrict__ weff) {
    __shared__ float c8[8][32];
    __shared__ float cred[32];
    __shared__ float ksr[2];
    __shared__ float ksv;
    const int blk = blockIdx.x;
    const int g = blk >> 5, ds = blk & 31;    // g = b*4+h; ds = d-channel
    const int bb = g >> 2, h = g & 3;
    const int t = threadIdx.x;
    const int e = t & 31, ii = t >> 5;        // ii 0..7
    float a = 0.f;
    const float* cp = ctx_part + (size_t)g * 128 * 1024 + ds * 32 + e;
#pragma unroll 4
    for (int i = ii * 16; i < ii * 16 + 16; ++i) a += cp[(size_t)i * 1024];
    c8[ii][e] = a;
    float ks = 0.f;
    if (t < 128) ks = ksum_part[((size_t)g * 128 + t) * 32 + ds];
#pragma unroll
    for (int off = 32; off > 0; off >>= 1) ks += __shfl_down(ks, off, 64);
    if (t < 128 && (t & 63) == 0) ksr[t >> 6] = ks;
    __syncthreads();
    if (t < 32) {
        float s = 0.f;
#pragma unroll
        for (int k = 0; k < 8; ++k) s += c8[k][t];
        cred[t] = s;
    }
    if (t == 0) ksv = ksr[0] + ksr[1];
    __syncthreads();
    if (t < 64) {
        const float* wrow = wout + t * HID + h * 32;
        float acc = 0.f;
#pragma unroll
        for (int e2 = 0; e2 < 32; ++e2) acc = fmaf(wrow[e2], cred[e2], acc);
        acc /= ksv;
        weff[((size_t)bb * 64 + t) * 128 + h * 32 + ds] = f2bf(acc);
    }
}

// ==== kC: y = Weff·q̂ from global frags; stats; y_t (pure PV, no LDS) =======
__global__ __launch_bounds__(256) void kC(const unsigned short* __restrict__ qs_frag,
        const unsigned short* __restrict__ weff, const float* __restrict__ bout,
        unsigned short* __restrict__ y_t, float* __restrict__ pstats) {
    __shared__ float red[8];
    const int t = threadIdx.x, wv = t >> 6, l = t & 63, lg = l >> 4, lc = l & 15;
    const int blk = blockIdx.x;
    const int b = blk >> 8, nblk = blk & 255;
    const int n0 = nblk * 128 + wv * 32;

    f32x4 acc[4][2] = {};   // [mt][s]
    const unsigned short* wb = weff + (size_t)b * 8192;
#pragma unroll
    for (int kk = 0; kk < 4; ++kk) {
        bf16x8 bq[2];
#pragma unroll
        for (int s = 0; s < 2; ++s) {
            int pos16 = nblk * 8 + wv * 2 + s;
            bq[s] = *(const bf16x8*)(qs_frag +
                ((size_t)(b * 2048 + pos16) * 4 + kk) * 512 + (size_t)l * 8);
        }
#pragma unroll
        for (int mt = 0; mt < 4; ++mt) {
            bf16x8 af = *(const bf16x8*)(wb + (size_t)(mt * 16 + lc) * 128 + kk * 32 + lg * 8);
#pragma unroll
            for (int s = 0; s < 2; ++s)
                acc[mt][s] = __builtin_amdgcn_mfma_f32_16x16x32_bf16(af, bq[s], acc[mt][s], 0, 0, 0);
        }
    }
    // bias + stats + y_t store ([n][o] bf16)
    float s1 = 0.f, s2 = 0.f;
#pragma unroll
    for (int mt = 0; mt < 4; ++mt) {
        float bo[4];
#pragma unroll
        for (int r = 0; r < 4; ++r) bo[r] = bout[mt * 16 + lg * 4 + r];
#pragma unroll
        for (int s = 0; s < 2; ++s) {
            u16x4 pk;
#pragma unroll
            for (int r = 0; r < 4; ++r) {
                float val = acc[mt][s][r] + bo[r];
                s1 += val;
                s2 = fmaf(val, val, s2);
                pk[r] = f2bf(val);
            }
            int n = n0 + s * 16 + lc;
            *(u16x4*)(y_t + ((size_t)b * N_SP + n) * 64 + mt * 16 + lg * 4) = pk;
        }
    }
#pragma unroll
    for (int off = 32; off > 0; off >>= 1) {
        s1 += __shfl_down(s1, off, 64);
        s2 += __shfl_down(s2, off, 64);
    }
    if (l == 0) { red[wv * 2] = s1; red[wv * 2 + 1] = s2; }
    __syncthreads();
    if (t == 0) {
        float S1 = red[0] + red[2] + red[4] + red[6];
        float S2 = red[1] + red[3] + red[5] + red[7];
        pstats[(b * 256 + nblk) * 2]     = S1;
        pstats[(b * 256 + nblk) * 2 + 1] = S2;
    }
}

// ==== kE: inline stats reduce (256 pairs), GN affine, y_t -> out ============
__global__ __launch_bounds__(256) void kE(const unsigned short* __restrict__ y_t,
        const float* __restrict__ pstats, const float* __restrict__ gnw,
        const float* __restrict__ gnb, float* __restrict__ out) {
    __shared__ float red[8];
    __shared__ float ms[2];
    __shared__ float w2s[64], b2s[64];
    const int t = threadIdx.x;
    const int blk = blockIdx.x;
    const int b = blk >> 9, nb = blk & 511;
    // reduce this batch's 256 stat pairs (redundant per block, L2-hot)
    float s1 = pstats[(b * 256 + t) * 2];
    float s2 = pstats[(b * 256 + t) * 2 + 1];
#pragma unroll
    for (int off = 32; off > 0; off >>= 1) {
        s1 += __shfl_down(s1, off, 64);
        s2 += __shfl_down(s2, off, 64);
    }
    if ((t & 63) == 0) { red[(t >> 6) * 2] = s1; red[(t >> 6) * 2 + 1] = s2; }
    __syncthreads();
    if (t == 0) {
        float S1 = red[0] + red[2] + red[4] + red[6];
        float S2 = red[1] + red[3] + red[5] + red[7];
        float mean = S1 / NGN;
        float var = S2 / NGN - mean * mean;
        ms[0] = mean; ms[1] = rsqrtf(var + GN_EPS_C);
    }
    __syncthreads();
    if (t < 64) {
        float w2 = gnw[t] * ms[1];
        w2s[t] = w2;
        b2s[t] = gnb[t] - ms[0] * w2;
    }
    __syncthreads();
    // n = nb*64 + (t&63): wave-contiguous out-writes (256 B per o-plane)
    const int n = nb * 64 + (t & 63), o0 = (t >> 6) * 16;
    const unsigned short* yp = y_t + ((size_t)b * N_SP + n) * 64 + o0;
    u16x8 v0 = *(const u16x8*)yp;
    u16x8 v1 = *(const u16x8*)(yp + 8);
    float* ob = out + (size_t)b * C_IN * N_SP + n;
#pragma unroll
    for (int j = 0; j < 8; ++j)
        ob[(size_t)(o0 + j) * N_SP] = fmaf(bf2f((unsigned short)v0[j]), w2s[o0 + j], b2s[o0 + j]);
#pragma unroll
    for (int j = 0; j < 8; ++j)
        ob[(size_t)(o0 + 8 + j) * N_SP] = fmaf(bf2f((unsigned short)v1[j]), w2s[o0 + 8 + j], b2s[o0 + 8 + j]);
}

extern "C" void kernel_launch(void* const* d_in, const int* in_sizes, int n_in,
                              void* d_out, int out_size, void* d_ws, size_t ws_size,
                              hipStream_t stream) {
    const float* x    = (const float*)d_in[0];
    const float* wqkv = (const float*)d_in[1];
    const float* wout = (const float*)d_in[2];
    const float* bout = (const float*)d_in[3];
    const float* gnw  = (const float*)d_in[4];
    const float* gnb  = (const float*)d_in[5];
    float* out = (float*)d_out;

    char* ws = (char*)d_ws;
    size_t off = 0;
    unsigned short* qs_frag = (unsigned short*)(ws + off); off += (size_t)NB * 2048 * 4 * 512 * 2;  // 16.8 MB
    float* ctx_part  = (float*)(ws + off); off += (size_t)8 * 128 * 1024 * 4;   // 4 MB
    float* ksum_part = (float*)(ws + off); off += (size_t)8 * 128 * 32 * 4;     // 128 KB
    unsigned short* weff = (unsigned short*)(ws + off); off += 2 * 8192 * 2;    // 32 KB
    unsigned short* y_t  = (unsigned short*)(ws + off); off += (size_t)NB * N_SP * 64 * 2;  // 8.4 MB
    float* pstats = (float*)(ws + off); off += NB * 256 * 2 * 4;

    kA<<<dim3(256), dim3(512), 0, stream>>>(x, wqkv, qs_frag, ctx_part, ksum_part);
    kB<<<dim3(256), dim3(256), 0, stream>>>(ctx_part, ksum_part, wout, weff);
    kC<<<dim3(512), dim3(256), 0, stream>>>(qs_frag, weff, bout, y_t, pstats);
    kE<<<dim3(1024), dim3(256), 0, stream>>>(y_t, pstats, gnw, gnb, out);
}